// Round 15
// baseline (565.127 us; speedup 1.0000x reference)
//
#include <hip/hip_runtime.h>
#include <hip/hip_fp16.h>
#include <math.h>

#define NB   16     // batch
#define IMG  128    // input image side
#define NANG 300
#define NDET 300
#define WB   148    // canvas live box: x,y in [76,224)

typedef _Float16 v2h __attribute__((ext_vector_type(2)));

// Gaussian taps: sigma_img -> 2^(-d^2/2); sigma_att -> 2^(-d^2/8). f64 normalize, f32 cast.
__device__ __constant__ float KE[9] = {
  (float)(0.00390625            / 3.0104144100214136),
  (float)(0.04419417382415922   / 3.0104144100214136),
  (float)(0.25                  / 3.0104144100214136),
  (float)(0.7071067811865476    / 3.0104144100214136),
  (float)(1.0                   / 3.0104144100214136),
  (float)(0.7071067811865476    / 3.0104144100214136),
  (float)(0.25                  / 3.0104144100214136),
  (float)(0.04419417382415922   / 3.0104144100214136),
  (float)(0.00390625            / 3.0104144100214136)
};
__device__ __constant__ float KA[17] = {
  (float)(0.00390625            / 6.019333926786741),
  (float)(0.014328188175072987  / 6.019333926786741),
  (float)(0.04419417382415922   / 6.019333926786741),
  (float)(0.11462550540058389   / 6.019333926786741),
  (float)(0.25                  / 6.019333926786741),
  (float)(0.4585020216023356    / 6.019333926786741),
  (float)(0.7071067811865476    / 6.019333926786741),
  (float)(0.9170040432046712    / 6.019333926786741),
  (float)(1.0                   / 6.019333926786741),
  (float)(0.9170040432046712    / 6.019333926786741),
  (float)(0.7071067811865476    / 6.019333926786741),
  (float)(0.4585020216023356    / 6.019333926786741),
  (float)(0.25                  / 6.019333926786741),
  (float)(0.11462550540058389   / 6.019333926786741),
  (float)(0.04419417382415922   / 6.019333926786741),
  (float)(0.014328188175072987  / 6.019333926786741),
  (float)(0.00390625            / 6.019333926786741)
};

__device__ __forceinline__ unsigned h16(float f) {
  return (unsigned)__half_as_ushort(__float2half_rn(f));
}
__device__ __forceinline__ unsigned pk16u(float a, float b) {
  return __builtin_bit_cast(unsigned, __builtin_amdgcn_cvt_pkrtz(a, b));
}
__device__ __forceinline__ float fdot2(unsigned q, unsigned w, float acc) {
  return __builtin_amdgcn_fdot2(__builtin_bit_cast(v2h, q), __builtin_bit_cast(v2h, w), acc, false);
}

// K1: fused pad+blur -> f16 quad canvas over the live box [76,224)^2.
// Q[y'][x'][b] = uint4{ E00|E01, E10|E11, A00|A01, A10|A11 } (f16 pairs; suffix
// (r,c) = (y+r, x+c); A pre-scaled 0.01). Whole 2x2 bilinear footprint of both
// images in ONE 16-B load for k_radon. Also zeroes the per-angle counters cnt[300]
// consumed by k_radon's fused dblur (ws is re-poisoned 0xAA before every launch).
__global__ void k_prep(const float* __restrict__ img, const float* __restrict__ att,
                       uint4* __restrict__ Q, unsigned* __restrict__ cnt) {
  __shared__ float sImg[25 * 25];
  __shared__ float sAtt[33 * 33];
  __shared__ float sEi[25 * 17];
  __shared__ float sAi[33 * 17];

  int tid = threadIdx.x;
  if (blockIdx.y == 0 && blockIdx.z == 0 && tid < 30)
    cnt[blockIdx.x * 30 + tid] = 0u;     // 10 blocks x 30 = 300 counters

  int tx = tid & 15, ty = tid >> 4;
  int X0 = blockIdx.x * 16;
  int Y0 = blockIdx.y * 16;
  int b  = blockIdx.z;
  const float* imb = img + b * IMG * IMG;
  const float* atb = att + b * IMG * IMG;
  for (int t = tid; t < 625; t += 256) {
    int r = t / 25, c = t - r * 25;
    int ir = Y0 - 14 + r, ic = X0 - 14 + c;
    bool v = (ir >= 0) & (ir < IMG) & (ic >= 0) & (ic < IMG);
    sImg[t] = v ? imb[ir * IMG + ic] : 0.f;
  }
  for (int t = tid; t < 1089; t += 256) {
    int r = t / 33, c = t - r * 33;
    int ir = Y0 - 18 + r, ic = X0 - 18 + c;
    bool v = (ir >= 0) & (ir < IMG) & (ic >= 0) & (ic < IMG);
    sAtt[t] = v ? atb[ir * IMG + ic] : 0.f;
  }
  __syncthreads();
  for (int t = tid; t < 425; t += 256) {
    int r = t / 17, c = t - r * 17;
    float acc = 0.f;
#pragma unroll
    for (int d = 0; d < 9; ++d) acc = fmaf(KE[d], sImg[r * 25 + c + d], acc);
    sEi[t] = acc;
  }
  for (int t = tid; t < 561; t += 256) {
    int r = t / 17, c = t - r * 17;
    float acc = 0.f;
#pragma unroll
    for (int d = 0; d < 17; ++d) acc = fmaf(KA[d], sAtt[r * 33 + c + d], acc);
    sAi[t] = acc;
  }
  __syncthreads();
  int xc = X0 + tx, yc = Y0 + ty;
  if (xc >= WB || yc >= WB) return;
  float E00 = 0.f, E01 = 0.f, E10 = 0.f, E11 = 0.f;
  float A00 = 0.f, A01 = 0.f, A10 = 0.f, A11 = 0.f;
#pragma unroll
  for (int d = 0; d < 9; ++d) {
    float k = KE[d];
    E00 = fmaf(k, sEi[(ty + d) * 17 + tx],     E00);
    E01 = fmaf(k, sEi[(ty + d) * 17 + tx + 1], E01);
    E10 = fmaf(k, sEi[(ty + 1 + d) * 17 + tx],     E10);
    E11 = fmaf(k, sEi[(ty + 1 + d) * 17 + tx + 1], E11);
  }
#pragma unroll
  for (int d = 0; d < 17; ++d) {
    float k = KA[d];
    A00 = fmaf(k, sAi[(ty + d) * 17 + tx],     A00);
    A01 = fmaf(k, sAi[(ty + d) * 17 + tx + 1], A01);
    A10 = fmaf(k, sAi[(ty + 1 + d) * 17 + tx],     A10);
    A11 = fmaf(k, sAi[(ty + 1 + d) * 17 + tx + 1], A11);
  }
  uint4 q;
  q.x = h16(E00) | (h16(E01) << 16);
  q.y = h16(E10) | (h16(E11) << 16);
  q.z = h16(0.01f * A00) | (h16(0.01f * A01) << 16);
  q.w = h16(0.01f * A10) | (h16(0.01f * A11) << 16);
  Q[(yc * WB + xc) * NB + b] = q;
}

// K2: radon (r12-validated LDS coordinate pipeline) + fused per-angle dblur.
// Radon: block 256 = 16 j x 16 b; per 16-sample chunk, Phase A computes 16
// coords/weights across lanes -> per-wave LDS; Phase B: broadcast ds_read_b128 +
// ONE dwordx4/sample + 4 fdot2. Coordinate clamp px,py->[76.5,222.0] before
// floor: identity in-chord; clamped samples hit all-zero rows/cols -> exact 0.
// Fusion: after writing S, each block release-arrives at cnt[a]; the 19th block
// (acquire) runs the 5-tap detector blur + scale for the whole angle -> out.
// 19 RMWs per counter line, 300 independent lines -> no hot-line serialization.
__global__ void __launch_bounds__(256)
k_radon(const uint4* __restrict__ P, float* __restrict__ S,
        const float* __restrict__ scale, float* __restrict__ out,
        unsigned* __restrict__ cnt) {
  __shared__ uint4 sLds[16 * 17];       // row jrow*17 + u ; 17-stride kills bank conflicts
  __shared__ unsigned sOld;

  int t = threadIdx.x;
  int b    = t & 15;
  int jrow = t >> 4;
  int j  = blockIdx.x * 16 + jrow;
  int a  = blockIdx.y;
  bool jvalid = j < NDET;

  float th = (float)a * (float)(3.14159265358979323846 / 299.0);
  float c = cosf(th), s = sinf(th);
  float xj = fmaf((float)j, (float)(2.0 / 299.0), -1.0f);
  float pb = fmaf(c,  xj, 1.0f) * 149.5f - 149.5f * s;
  float qb = fmaf(-s, xj, 1.0f) * 149.5f - 149.5f * c;
  const float L = 76.5f, H = 222.5f;
  float lo = 0.f, hi = jvalid ? 299.0f : -1.0f;
  if (s > 1e-6f) {
    float inv = 1.0f / s;
    lo = fmaxf(lo, (L - pb) * inv); hi = fminf(hi, (H - pb) * inv);
  } else if (pb < L || pb > H) { hi = -1.f; }
  if (fabsf(c) > 1e-6f) {
    float inv = 1.0f / c;
    float t0 = (L - qb) * inv, t1 = (H - qb) * inv;
    lo = fmaxf(lo, fminf(t0, t1)); hi = fminf(hi, fmaxf(t0, t1));
  } else if (qb < L || qb > H) { hi = -1.f; }

  // wave-uniform union bounds over this wave's 4 j's
  float lo_w = fminf(lo, __shfl_xor(lo, 16));
  lo_w = fminf(lo_w, __shfl_xor(lo_w, 32));
  float hi_w = fmaxf(hi, __shfl_xor(hi, 16));
  hi_w = fmaxf(hi_w, __shfl_xor(hi_w, 32));
  int i0w  = __builtin_amdgcn_readfirstlane((int)floorf(fmaxf(lo_w, 0.f)));
  int ihiw = __builtin_amdgcn_readfirstlane((int)floorf(hi_w));

  uint4* entW = &sLds[jrow * 17 + b];
  const uint4* entR = &sLds[jrow * 17];
  const char* Pcb = (const char*)P + b * 16;
  const int PIXBASE = -76 * 149 * 256;

  float sE0 = 0.f, sE1 = 0.f, sA0 = 0.f, sA1 = 0.f;
  float fib = (float)i0w + (float)b;

  for (int ib = i0w; ib <= ihiw; ib += 16, fib += 16.f) {
    {
      float px = fmaf(fib, s, pb);
      float py = fmaf(fib, c, qb);
      px = fminf(fmaxf(px, 76.5f), 222.0f);
      py = fminf(fmaxf(py, 76.5f), 222.0f);
      float x0f = floorf(px), y0f = floorf(py);
      float wx = px - x0f, wy = py - y0f;
      int idx = (int)fmaf(y0f, (float)WB, x0f);
      int off = (idx << 8) + PIXBASE;
      float omx = 1.0f - wx, omy = 1.0f - wy;
      unsigned w0 = pk16u(omy * omx, omy * wx);
      unsigned w1 = pk16u(wy * omx,  wy * wx);
      *entW = make_uint4((unsigned)off, w0, w1, w1);
    }
    __builtin_amdgcn_wave_barrier();
#pragma unroll
    for (int g = 0; g < 2; ++g) {
      uint4 e[8];
#pragma unroll
      for (int u = 0; u < 8; ++u) e[u] = entR[g * 8 + u];
      uint4 q[8];
#pragma unroll
      for (int u = 0; u < 8; ++u)
        q[u] = *(const uint4*)(Pcb + (int)e[u].x);
#pragma unroll
      for (int u = 0; u < 8; ++u) {
        sE0 = fdot2(q[u].x, e[u].y, sE0);
        sE1 = fdot2(q[u].y, e[u].z, sE1);
        sA0 = fdot2(q[u].z, e[u].y, sA0);
        sA1 = fdot2(q[u].w, e[u].z, sA1);
      }
    }
    __builtin_amdgcn_wave_barrier();
  }
  if (jvalid) {
    float sumE = sE0 + sE1, sumA = sA0 + sA1;
    S[(a * NB + b) * NDET + j] = sumE * expf(-2.0f * sumA);  // VOXEL_MM = 2
  }

  // ---- fused per-angle dblur (runs in the 19th-arriving block of this angle) ----
  __syncthreads();                      // all waves' S stores issued & waited
  if (t == 0) {
    __threadfence();                    // publish this block's S (device scope, wbL2)
    sOld = __hip_atomic_fetch_add(&cnt[a], 1u, __ATOMIC_ACQ_REL,
                                  __HIP_MEMORY_SCOPE_AGENT);
  }
  __syncthreads();
  if (sOld == 18u) {                    // last block for angle a; acquire done above
    float u = fabsf(c) + fabsf(s);      // bw = 2u
    float u2 = u * u;
    float e1 = exp2f(-2.0f * u2);
    float e2 = exp2f(-8.0f * u2);
    float norm = 1.0f / (1.0f + 2.0f * (e1 + e2));
    float w2c = norm, w1c = e1 * norm, w0c = e2 * norm;
    for (int bb = 0; bb < NB; ++bb) {
      float sc = scale[bb];
      const float* row = S + (a * NB + bb) * NDET;
      float* orow = out + (bb * NANG + a) * NDET;
      for (int jj = t; jj < NDET; jj += 256) {
        float acc = 0.f;
#pragma unroll
        for (int tt = -2; tt <= 2; ++tt) {
          int jr = jj + tt;
          if (jr < 0) jr = -jr;
          if (jr > 299) jr = 598 - jr;
          float w = (tt == 0) ? w2c : ((tt == 1 || tt == -1) ? w1c : w0c);
          acc = fmaf(w, row[jr], acc);
        }
        orow[jj] = acc * sc;
      }
    }
  }
}

extern "C" void kernel_launch(void* const* d_in, const int* in_sizes, int n_in,
                              void* d_out, int out_size, void* d_ws, size_t ws_size,
                              hipStream_t stream) {
  const float* img   = (const float*)d_in[0];
  const float* att   = (const float*)d_in[1];
  const float* scale = (const float*)d_in[2];
  float* out = (float*)d_out;
  float* ws  = (float*)d_ws;

  // ws layout (floats): Q 148*148*16 uint4 (5.61 MB) | S 300*300*16 (5.76 MB) | cnt[300]
  uint4*    Q   = (uint4*)ws;
  float*    S   = ws + 1401856;
  unsigned* cnt = (unsigned*)(ws + 2841856);

  k_prep <<<dim3(10, 10, NB), 256, 0, stream>>>(img, att, Q, cnt);
  k_radon<<<dim3(19, NANG),   256, 0, stream>>>(Q, S, scale, out, cnt);
}

// Round 16
// 160.727 us; speedup vs baseline: 3.5161x; 3.5161x over previous
//
#include <hip/hip_runtime.h>
#include <hip/hip_fp16.h>
#include <math.h>

#define NB   16     // batch
#define IMG  128    // input image side
#define NANG 300
#define NDET 300
#define WB   148    // canvas live box: x,y in [76,224)

typedef _Float16 v2h __attribute__((ext_vector_type(2)));

// Gaussian taps: sigma_img -> 2^(-d^2/2); sigma_att -> 2^(-d^2/8). f64 normalize, f32 cast.
__device__ __constant__ float KE[9] = {
  (float)(0.00390625            / 3.0104144100214136),
  (float)(0.04419417382415922   / 3.0104144100214136),
  (float)(0.25                  / 3.0104144100214136),
  (float)(0.7071067811865476    / 3.0104144100214136),
  (float)(1.0                   / 3.0104144100214136),
  (float)(0.7071067811865476    / 3.0104144100214136),
  (float)(0.25                  / 3.0104144100214136),
  (float)(0.04419417382415922   / 3.0104144100214136),
  (float)(0.00390625            / 3.0104144100214136)
};
__device__ __constant__ float KA[17] = {
  (float)(0.00390625            / 6.019333926786741),
  (float)(0.014328188175072987  / 6.019333926786741),
  (float)(0.04419417382415922   / 6.019333926786741),
  (float)(0.11462550540058389   / 6.019333926786741),
  (float)(0.25                  / 6.019333926786741),
  (float)(0.4585020216023356    / 6.019333926786741),
  (float)(0.7071067811865476    / 6.019333926786741),
  (float)(0.9170040432046712    / 6.019333926786741),
  (float)(1.0                   / 6.019333926786741),
  (float)(0.9170040432046712    / 6.019333926786741),
  (float)(0.7071067811865476    / 6.019333926786741),
  (float)(0.4585020216023356    / 6.019333926786741),
  (float)(0.25                  / 6.019333926786741),
  (float)(0.11462550540058389   / 6.019333926786741),
  (float)(0.04419417382415922   / 6.019333926786741),
  (float)(0.014328188175072987  / 6.019333926786741),
  (float)(0.00390625            / 6.019333926786741)
};

__device__ __forceinline__ unsigned h16(float f) {
  return (unsigned)__half_as_ushort(__float2half_rn(f));
}
__device__ __forceinline__ unsigned pk16u(float a, float b) {
  return __builtin_bit_cast(unsigned, __builtin_amdgcn_cvt_pkrtz(a, b));
}
__device__ __forceinline__ float fdot2(unsigned q, unsigned w, float acc) {
  return __builtin_amdgcn_fdot2(__builtin_bit_cast(v2h, q), __builtin_bit_cast(v2h, w), acc, false);
}

// K1: fused pad+blur -> f16 quad canvas over the live box [76,224)^2 (r12-proven).
// Q[y'][x'][b] = uint4{ E00|E01, E10|E11, A00|A01, A10|A11 } (f16 pairs; suffix
// (r,c) = (y+r, x+c); A pre-scaled 0.01). Whole 2x2 bilinear footprint of both
// images in ONE 16-B load for k_radon.
__global__ void k_prep(const float* __restrict__ img, const float* __restrict__ att,
                       uint4* __restrict__ Q) {
  __shared__ float sImg[25 * 25];
  __shared__ float sAtt[33 * 33];
  __shared__ float sEi[25 * 17];
  __shared__ float sAi[33 * 17];

  int tid = threadIdx.x;
  int tx = tid & 15, ty = tid >> 4;
  int X0 = blockIdx.x * 16;
  int Y0 = blockIdx.y * 16;
  int b  = blockIdx.z;
  const float* imb = img + b * IMG * IMG;
  const float* atb = att + b * IMG * IMG;
  for (int t = tid; t < 625; t += 256) {
    int r = t / 25, c = t - r * 25;
    int ir = Y0 - 14 + r, ic = X0 - 14 + c;
    bool v = (ir >= 0) & (ir < IMG) & (ic >= 0) & (ic < IMG);
    sImg[t] = v ? imb[ir * IMG + ic] : 0.f;
  }
  for (int t = tid; t < 1089; t += 256) {
    int r = t / 33, c = t - r * 33;
    int ir = Y0 - 18 + r, ic = X0 - 18 + c;
    bool v = (ir >= 0) & (ir < IMG) & (ic >= 0) & (ic < IMG);
    sAtt[t] = v ? atb[ir * IMG + ic] : 0.f;
  }
  __syncthreads();
  for (int t = tid; t < 425; t += 256) {
    int r = t / 17, c = t - r * 17;
    float acc = 0.f;
#pragma unroll
    for (int d = 0; d < 9; ++d) acc = fmaf(KE[d], sImg[r * 25 + c + d], acc);
    sEi[t] = acc;
  }
  for (int t = tid; t < 561; t += 256) {
    int r = t / 17, c = t - r * 17;
    float acc = 0.f;
#pragma unroll
    for (int d = 0; d < 17; ++d) acc = fmaf(KA[d], sAtt[r * 33 + c + d], acc);
    sAi[t] = acc;
  }
  __syncthreads();
  int xc = X0 + tx, yc = Y0 + ty;
  if (xc >= WB || yc >= WB) return;
  float E00 = 0.f, E01 = 0.f, E10 = 0.f, E11 = 0.f;
  float A00 = 0.f, A01 = 0.f, A10 = 0.f, A11 = 0.f;
#pragma unroll
  for (int d = 0; d < 9; ++d) {
    float k = KE[d];
    E00 = fmaf(k, sEi[(ty + d) * 17 + tx],     E00);
    E01 = fmaf(k, sEi[(ty + d) * 17 + tx + 1], E01);
    E10 = fmaf(k, sEi[(ty + 1 + d) * 17 + tx],     E10);
    E11 = fmaf(k, sEi[(ty + 1 + d) * 17 + tx + 1], E11);
  }
#pragma unroll
  for (int d = 0; d < 17; ++d) {
    float k = KA[d];
    A00 = fmaf(k, sAi[(ty + d) * 17 + tx],     A00);
    A01 = fmaf(k, sAi[(ty + d) * 17 + tx + 1], A01);
    A10 = fmaf(k, sAi[(ty + 1 + d) * 17 + tx],     A10);
    A11 = fmaf(k, sAi[(ty + 1 + d) * 17 + tx + 1], A11);
  }
  uint4 q;
  q.x = h16(E00) | (h16(E01) << 16);
  q.y = h16(E10) | (h16(E11) << 16);
  q.z = h16(0.01f * A00) | (h16(0.01f * A01) << 16);
  q.w = h16(0.01f * A10) | (h16(0.01f * A11) << 16);
  Q[(yc * WB + xc) * NB + b] = q;
}

// K2: radon (r12 LDS coordinate pipeline) + BLOCK-LOCAL fused detector blur.
// Block = 576 threads = 36 jrow x 16 b (9 waves): a 32-j strip of angle a plus a
// 2-j halo on each side, so the 5-tap j-blur of the strip needs only in-block S.
// S stays in LDS; after one __syncthreads, threads (32 j x 16 b) apply the blur
// + scale and write out[b][a][j] directly. NO cross-block sync (r13/r14/r15
// showed any agent-scope sync costs ~100+ us on non-coherent per-XCD L2).
// Radon per chunk: Phase A computes 16 coords/weights across lanes -> per-wave
// LDS; Phase B: broadcast ds_read_b128 + ONE dwordx4/sample + 4 fdot2.
// Coordinate clamp px,py->[76.5,222.0] before floor: identity in-chord; clamped
// samples hit all-zero rows/cols {76,77,222,223} -> exact 0, addresses in-bounds.
__global__ void __launch_bounds__(576)
k_radon(const uint4* __restrict__ P, const float* __restrict__ scale,
        float* __restrict__ out) {
  __shared__ uint4 sLds[36 * 17];       // coord pipe: row jrow*17 + u
  __shared__ float sS[36 * 17];         // per-block sinogram strip (stride 17)

  int t = threadIdx.x;
  int b    = t & 15;
  int jrow = t >> 4;                    // 0..35
  int a  = blockIdx.y;
  int jstart = blockIdx.x * 32 - 2;     // halo: block covers j in [jstart, jstart+36)
  int j  = jstart + jrow;
  bool jvalid = (unsigned)j < (unsigned)NDET;

  float th = (float)a * (float)(3.14159265358979323846 / 299.0);
  float c = cosf(th), s = sinf(th);
  float xj = fmaf((float)j, (float)(2.0 / 299.0), -1.0f);
  float pb = fmaf(c,  xj, 1.0f) * 149.5f - 149.5f * s;
  float qb = fmaf(-s, xj, 1.0f) * 149.5f - 149.5f * c;
  const float L = 76.5f, H = 222.5f;
  float lo = 0.f, hi = jvalid ? 299.0f : -1.0f;
  if (s > 1e-6f) {
    float inv = 1.0f / s;
    lo = fmaxf(lo, (L - pb) * inv); hi = fminf(hi, (H - pb) * inv);
  } else if (pb < L || pb > H) { hi = -1.f; }
  if (fabsf(c) > 1e-6f) {
    float inv = 1.0f / c;
    float t0 = (L - qb) * inv, t1 = (H - qb) * inv;
    lo = fmaxf(lo, fminf(t0, t1)); hi = fminf(hi, fmaxf(t0, t1));
  } else if (qb < L || qb > H) { hi = -1.f; }

  // wave-uniform union bounds over this wave's 4 j's
  float lo_w = fminf(lo, __shfl_xor(lo, 16));
  lo_w = fminf(lo_w, __shfl_xor(lo_w, 32));
  float hi_w = fmaxf(hi, __shfl_xor(hi, 16));
  hi_w = fmaxf(hi_w, __shfl_xor(hi_w, 32));
  int i0w  = __builtin_amdgcn_readfirstlane((int)floorf(fmaxf(lo_w, 0.f)));
  int ihiw = __builtin_amdgcn_readfirstlane((int)floorf(hi_w));

  uint4* entW = &sLds[jrow * 17 + b];
  const uint4* entR = &sLds[jrow * 17];
  const char* Pcb = (const char*)P + b * 16;
  const int PIXBASE = -76 * 149 * 256;

  float sE0 = 0.f, sE1 = 0.f, sA0 = 0.f, sA1 = 0.f;
  float fib = (float)i0w + (float)b;

  for (int ib = i0w; ib <= ihiw; ib += 16, fib += 16.f) {
    {
      float px = fmaf(fib, s, pb);
      float py = fmaf(fib, c, qb);
      px = fminf(fmaxf(px, 76.5f), 222.0f);
      py = fminf(fmaxf(py, 76.5f), 222.0f);
      float x0f = floorf(px), y0f = floorf(py);
      float wx = px - x0f, wy = py - y0f;
      int idx = (int)fmaf(y0f, (float)WB, x0f);
      int off = (idx << 8) + PIXBASE;
      float omx = 1.0f - wx, omy = 1.0f - wy;
      unsigned w0 = pk16u(omy * omx, omy * wx);
      unsigned w1 = pk16u(wy * omx,  wy * wx);
      *entW = make_uint4((unsigned)off, w0, w1, w1);
    }
    __builtin_amdgcn_wave_barrier();
#pragma unroll
    for (int g = 0; g < 2; ++g) {
      uint4 e[8];
#pragma unroll
      for (int u = 0; u < 8; ++u) e[u] = entR[g * 8 + u];
      uint4 q[8];
#pragma unroll
      for (int u = 0; u < 8; ++u)
        q[u] = *(const uint4*)(Pcb + (int)e[u].x);
#pragma unroll
      for (int u = 0; u < 8; ++u) {
        sE0 = fdot2(q[u].x, e[u].y, sE0);
        sE1 = fdot2(q[u].y, e[u].z, sE1);
        sA0 = fdot2(q[u].z, e[u].y, sA0);
        sA1 = fdot2(q[u].w, e[u].z, sA1);
      }
    }
    __builtin_amdgcn_wave_barrier();
  }
  {
    float sumE = sE0 + sE1, sumA = sA0 + sA1;
    // invalid j: loop never ran -> sumE=0, write 0 (slot never read anyway)
    sS[jrow * 17 + b] = jvalid ? sumE * expf(-2.0f * sumA) : 0.f;  // VOXEL_MM = 2
  }
  __syncthreads();

  // ---- block-local detector blur + scale ----
  if (t < 512) {
    int jj = t & 31, bb = t >> 5;       // lanes: consecutive j, same b -> coalesced out
    int jglob = blockIdx.x * 32 + jj;
    if (jglob < NDET) {
      float u = fabsf(c) + fabsf(s);    // bw = 2u (c,s uniform across block)
      float u2 = u * u;
      float e1 = exp2f(-2.0f * u2);
      float e2 = exp2f(-8.0f * u2);
      float norm = 1.0f / (1.0f + 2.0f * (e1 + e2));
      float w2c = norm, w1c = e1 * norm, w0c = e2 * norm;
      float acc = 0.f;
#pragma unroll
      for (int tt = -2; tt <= 2; ++tt) {
        int jr = jglob + tt;
        if (jr < 0) jr = -jr;
        if (jr > 299) jr = 598 - jr;
        int lr = jr - jstart;           // in [0,36) by construction
        float w = (tt == 0) ? w2c : ((tt == 1 || tt == -1) ? w1c : w0c);
        acc = fmaf(w, sS[lr * 17 + bb], acc);
      }
      out[(bb * NANG + a) * NDET + jglob] = acc * scale[bb];
    }
  }
}

extern "C" void kernel_launch(void* const* d_in, const int* in_sizes, int n_in,
                              void* d_out, int out_size, void* d_ws, size_t ws_size,
                              hipStream_t stream) {
  const float* img   = (const float*)d_in[0];
  const float* att   = (const float*)d_in[1];
  const float* scale = (const float*)d_in[2];
  float* out = (float*)d_out;
  float* ws  = (float*)d_ws;

  // ws layout (floats): Q 148*148*16 uint4 (5.61 MB)
  uint4* Q = (uint4*)ws;

  k_prep <<<dim3(10, 10, NB), 256, 0, stream>>>(img, att, Q);
  k_radon<<<dim3(10, NANG),   576, 0, stream>>>(Q, scale, out);
}